// Round 12
// baseline (2566.488 us; speedup 1.0000x reference)
//
#include <hip/hip_runtime.h>
#include <hip/hip_fp16.h>
#include <stdint.h>
#include <math.h>

#define NB    64      // batch
#define NT    2048    // time steps
#define NF    256     // input features
#define NH    256     // hidden
#define NG    768     // 3*NH
#define NPROD 192     // producer blocks (xi GEMM)
#define GRPT  16      // timesteps per ticket group
#define NGRP  (NT / GRPT)

#define LOG2E  1.44269504088896340736f

typedef unsigned int u32;
typedef _Float16 f16;
typedef f16 half2v __attribute__((ext_vector_type(2)));

__device__ __forceinline__ u32 packpair(float a, float b) {
    return __builtin_bit_cast(u32, __builtin_amdgcn_cvt_pkrtz(a, b));   // v_cvt_pkrtz_f16_f32
}
__device__ __forceinline__ float fdot2u(u32 w, u32 h, float acc) {      // f32-acc dot2
#if __has_builtin(__builtin_amdgcn_fdot2)
    return __builtin_amdgcn_fdot2(__builtin_bit_cast(half2v, w),
                                  __builtin_bit_cast(half2v, h), acc, false);
#else
    half2v wv = __builtin_bit_cast(half2v, w), hv = __builtin_bit_cast(half2v, h);
    return fmaf((float)wv[1], (float)hv[1], fmaf((float)wv[0], (float)hv[0], acc));
#endif
}
// sum across the 4 lanes of a quad — 2 DPP adds
__device__ __forceinline__ float quad_sum(float v) {
    int i = __builtin_bit_cast(int, v);
    v += __builtin_bit_cast(float, __builtin_amdgcn_update_dpp(0, i, 0xB1, 0xF, 0xF, true)); // [1,0,3,2]
    i = __builtin_bit_cast(int, v);
    v += __builtin_bit_cast(float, __builtin_amdgcn_update_dpp(0, i, 0x4E, 0xF, 0xF, true)); // [2,3,0,1]
    return v;
}

// ============ Fused kernel: 256 blocks x 1024 threads ============
// blocks [64,256): PRODUCERS — xi[b][t][g*256+u] = (x[b][t]@Wi + r/z bias),
//   PRE-SCALED by log2e (r,z) / 2*log2e (n) so consumer gates use raw exp2.
//   f32 PLANAR layout -> consumer reads are 3 perfectly-coalesced dwords
//   (round 11's [u][3] interleave cost 3x cache lines per load). Written as
//   agent-scope relaxed atomic stores (coherence point; consumer L2s are not
//   cross-coherent). After each t: __syncthreads (drains every wave's vmcnt)
//   then RELEASE fetch_add on groups[t/16]. Producers never wait.
// blocks [0,64): CONSUMERS — scan with 16-step-unrolled groups; group poll
//   folded into the step-tail barrier (tid0 polls g+2 between ds_write and
//   the step's own __syncthreads; no extra barriers).
__global__ __attribute__((amdgpu_flat_work_group_size(1024, 1024),
                          amdgpu_waves_per_eu(4, 4))) void gru_fused(
        const float* __restrict__ carry,
        const float* __restrict__ x,
        const float* __restrict__ Wi,
        const float* __restrict__ Wh,
        const float* __restrict__ bh,
        float* __restrict__ xi,        // f32 planar [b][t][768], pre-scaled
        int*   __restrict__ groups,
        float* __restrict__ out_carry,
        float* __restrict__ out_hidden) {
    const int tid = threadIdx.x;

    if (blockIdx.x >= NB) {
        // ======================= PRODUCER =======================
        __shared__ u32 xs2[16][128];                  // 16 rows, packed f16 pairs
        const int p = blockIdx.x - NB;

        for (int t = p; t < NT; t += NPROD) {
            #pragma unroll 1
            for (int pass = 0; pass < 4; ++pass) {    // 16 batches per pass
                const int b0 = pass * 16;
                for (int i = tid; i < 16 * 128; i += 1024) {
                    const int r = i >> 7, pc = i & 127;
                    const float2 v = *(const float2*)&x[((size_t)(b0 + r) * NT + t) * NF + pc * 2];
                    xs2[r][pc] = packpair(v.x, v.y);
                }
                __syncthreads();

                if (tid < NG) {
                    float acc[16];
                    #pragma unroll
                    for (int r = 0; r < 16; ++r) acc[r] = 0.f;
                    for (int kp = 0; kp < 128; ++kp) {
                        const u32 wp = packpair(Wi[(size_t)(2 * kp) * NG + tid],
                                                Wi[(size_t)(2 * kp + 1) * NG + tid]);
                        #pragma unroll
                        for (int r = 0; r < 16; ++r)
                            acc[r] = fdot2u(wp, xs2[r][kp], acc[r]);
                    }
                    const float bias  = (tid < 512) ? bh[tid] : 0.f;        // fold r/z bias
                    const float scale = (tid < 512) ? LOG2E : 2.f * LOG2E;  // exp2 pre-scale
                    #pragma unroll
                    for (int r = 0; r < 16; ++r) {
                        const u32 v = __builtin_bit_cast(u32, (acc[r] + bias) * scale);
                        __hip_atomic_store((u32*)xi + ((size_t)(b0 + r) * NT + t) * NG + tid,
                                           v, __ATOMIC_RELAXED, __HIP_MEMORY_SCOPE_AGENT);
                    }
                }
                __syncthreads();   // xs2 reuse safe + every wave's vmcnt drained
            }
            if (tid == 0)
                __hip_atomic_fetch_add(&groups[t >> 4], 1,
                                       __ATOMIC_RELEASE, __HIP_MEMORY_SCOPE_AGENT);
        }
        return;
    }

    // ======================= CONSUMER =======================
    __shared__ u32 hsh[2][4][136];     // [buf][replica][128 pairs + pad]
    const int b   = blockIdx.x;
    const int u   = tid >> 2;          // unit 0..255
    const int kc  = tid & 3;           // k-chunk 0..3
    const int k0  = kc * 64;

    // register-stationary Wh, pre-scaled for exp2 gates:
    // gates r,z: * log2e ; gate n: * 2*log2e (tanh(y)=1-2/(1+e^{2y}))
    u32 wh2[3][32];
    #pragma unroll
    for (int j = 0; j < 3; ++j) {
        const float s = (j < 2) ? LOG2E : 2.f * LOG2E;
        const float* wp = &Wh[(size_t)k0 * NG + j * 256 + u];
        #pragma unroll
        for (int pp = 0; pp < 32; ++pp) {
            wh2[j][pp] = packpair(wp[0] * s, wp[NG] * s);
            wp += 2 * (size_t)NG;
        }
    }
    const float bn2 = bh[512 + u] * (2.f * LOG2E);

    float hreg = carry[(size_t)b * NH + u];
    ((f16*)&hsh[0][kc][0])[u] = (f16)hreg;

    // wait for xi groups 0 and 1 (group 0's steps prefetch into group 1)
    if (tid == 0) {
        while (__hip_atomic_load(&groups[0], __ATOMIC_ACQUIRE, __HIP_MEMORY_SCOPE_AGENT) < GRPT)
            __builtin_amdgcn_s_sleep(2);
        while (__hip_atomic_load(&groups[1], __ATOMIC_ACQUIRE, __HIP_MEMORY_SCOPE_AGENT) < GRPT)
            __builtin_amdgcn_s_sleep(2);
    }
    __syncthreads();

    const float* xb = xi + (size_t)b * NT * NG;    // planar: 3 coalesced dwords/step
    float xr = xb[u], xz = xb[256 + u], xn = xb[512 + u];
    xb += NG;
    float* op = out_hidden + (size_t)b * NT * NH + u;

#define D3(p, hc) { a0 = fdot2u(wh2[0][p], hc, a0); \
                    a1 = fdot2u(wh2[1][p], hc, a1); \
                    a2 = fdot2u(wh2[2][p], hc, a2); }

    for (int g = 0; g < NGRP; ++g) {
        #pragma unroll
        for (int j = 0; j < GRPT; ++j) {       // fully unrolled: parity static
            const int RB = j & 1, WB = RB ^ 1;
            const uint4* hp4 = (const uint4*)&hsh[RB][kc][kc * 32];
            float a0 = 0.f, a1 = 0.f, a2 = 0.f;
            #pragma unroll
            for (int ph = 0; ph < 4; ++ph) {
                const uint4 hA = hp4[2 * ph], hB = hp4[2 * ph + 1];
                D3(8 * ph + 0, hA.x); D3(8 * ph + 1, hA.y);
                D3(8 * ph + 2, hA.z); D3(8 * ph + 3, hA.w);
                D3(8 * ph + 4, hB.x); D3(8 * ph + 5, hB.y);
                D3(8 * ph + 6, hB.z); D3(8 * ph + 7, hB.w);
            }
            a0 = quad_sum(a0); a1 = quad_sum(a1); a2 = quad_sum(a2);

            // gates, exp2-native (all inputs pre-scaled by log2e / 2log2e)
            const float rg  = __builtin_amdgcn_rcpf(1.f + exp2f(-(xr + a0)));
            const float zg  = __builtin_amdgcn_rcpf(1.f + exp2f(-(xz + a1)));
            const float tt2 = xn + rg * (a2 + bn2);
            const float ng  = 1.f - 2.f * __builtin_amdgcn_rcpf(1.f + exp2f(tt2));
            const float hn  = ng + zg * (hreg - ng);
            hreg = hn;

            // tail: global ops first (whole next step to complete), LDS last
            if (kc == 0) *op = hn;
            op += NH;
            xr = xb[u]; xz = xb[256 + u]; xn = xb[512 + u];   // prefetch t+1
            xb += NG;
            ((f16*)&hsh[WB][kc][0])[u] = (f16)hn;             // lane kc -> replica kc

            if (j == GRPT - 1 && g + 2 < NGRP && tid == 0) {  // poll folded into step barrier
                while (__hip_atomic_load(&groups[g + 2], __ATOMIC_ACQUIRE,
                                         __HIP_MEMORY_SCOPE_AGENT) < GRPT)
                    __builtin_amdgcn_s_sleep(2);
            }
            __syncthreads();
        }
    }
#undef D3

    if (kc == 0) out_carry[(size_t)b * NH + u] = hreg;
}

// ================= host =================
extern "C" void kernel_launch(void* const* d_in, const int* in_sizes, int n_in,
                              void* d_out, int out_size, void* d_ws, size_t ws_size,
                              hipStream_t stream) {
    const float* carry = (const float*)d_in[0];
    const float* x     = (const float*)d_in[1];
    const float* Wi    = (const float*)d_in[2];
    const float* Wh    = (const float*)d_in[3];
    const float* bh    = (const float*)d_in[4];

    float* out_carry  = (float*)d_out;
    float* out_hidden = out_carry + (size_t)NB * NH;

    // layout: [groups: 512B @0] [pad to 4KB] [xi f32: 402.7MB] (ws proven >= this, round 1)
    int*   groups = (int*)d_ws;
    float* xi     = (float*)((char*)d_ws + 4096);

    hipMemsetAsync(groups, 0, NGRP * sizeof(int), stream);
    gru_fused<<<dim3(NB + NPROD), dim3(1024), 0, stream>>>(
        carry, x, Wi, Wh, bh, xi, groups, out_carry, out_hidden);
}